// Round 18
// baseline (1022.668 us; speedup 1.0000x reference)
//
#include <hip/hip_runtime.h>
#include <cstddef>

#define NUM_INST 32
#define EPS_IN 1e-5f

__device__ __forceinline__ int reflect_idx(int i, int n) {
    if (i < 0) i = -i;
    else if (i >= n) i = 2 * n - 2 - i;
    return i;
}

__device__ __forceinline__ float tanh_fast(float v) {
    float a = fminf(fmaxf(v, -9.f), 9.f);
    float e = __expf(2.f * a);
    return (e - 1.f) / (e + 1.f);
}

// ---------------- L0: 7x7 reflect conv 3->16, spill-free (acc[2][16]) --------
// (256,8): 8 blocks/CU (LDS 19.9KB x 8 = 159.4KB).
template<int CIN, int COUT>
__global__ void __launch_bounds__(256, 8)
conv7_l0(const float* __restrict__ x, const float* __restrict__ w,
         const float* __restrict__ bias, float* __restrict__ y, int H, int W)
{
    __shared__ float wsm[CIN * 49 * COUT];     // [ic][tap][oc]
    __shared__ float tile[CIN][38 * 23];       // 38 rows x 22 cols, stride 23
    const int tid = threadIdx.x;
    const int b = blockIdx.z;

    for (int idx = tid; idx < CIN * 49 * COUT; idx += 256) {
        int oc = idx % COUT;
        int r  = idx / COUT;
        wsm[idx] = w[(size_t)oc * CIN * 49 + r];
    }
    const int oh_base = blockIdx.y * 32, ow_base = blockIdx.x * 16;
    for (int idx = tid; idx < CIN * 38 * 22; idx += 256) {
        int c  = idx / (38 * 22);
        int rr = idx % (38 * 22);
        int r  = rr / 22, col = rr % 22;
        int gy = reflect_idx(oh_base - 3 + r, H);
        int gx = reflect_idx(ow_base - 3 + col, W);
        tile[c][r * 23 + col] = x[((size_t)(b * CIN + c)) * H * W + (size_t)gy * W + gx];
    }
    __syncthreads();

    const int row = tid >> 3;
    const int col2 = (tid & 7) * 2;

    float acc[2][COUT];
#pragma unroll
    for (int o = 0; o < COUT; ++o) {
        float bv = bias[o];
        acc[0][o] = bv; acc[1][o] = bv;
    }

#pragma unroll
    for (int ic = 0; ic < CIN; ++ic) {
        const float* tp = &tile[ic][0];
        const float4* wp4 = (const float4*)&wsm[ic * 49 * COUT];
#pragma unroll
        for (int kh = 0; kh < 7; ++kh) {
            float rv[8];
#pragma unroll
            for (int i = 0; i < 8; ++i) rv[i] = tp[(row + kh) * 23 + col2 + i];
#pragma unroll
            for (int kw = 0; kw < 7; ++kw) {
#pragma unroll
                for (int o4 = 0; o4 < COUT / 4; ++o4) {
                    float4 wv = wp4[(kh * 7 + kw) * (COUT / 4) + o4];
                    acc[0][o4 * 4 + 0] += rv[kw] * wv.x;
                    acc[0][o4 * 4 + 1] += rv[kw] * wv.y;
                    acc[0][o4 * 4 + 2] += rv[kw] * wv.z;
                    acc[0][o4 * 4 + 3] += rv[kw] * wv.w;
                    acc[1][o4 * 4 + 0] += rv[kw + 1] * wv.x;
                    acc[1][o4 * 4 + 1] += rv[kw + 1] * wv.y;
                    acc[1][o4 * 4 + 2] += rv[kw + 1] * wv.z;
                    acc[1][o4 * 4 + 3] += rv[kw + 1] * wv.w;
                }
            }
        }
    }

    const int oh = oh_base + row, ow0 = ow_base + col2;
#pragma unroll
    for (int o = 0; o < COUT; ++o) {
        float2 st;
        st.x = acc[0][o]; st.y = acc[1][o];
        *(float2*)&y[(((size_t)b * COUT + o) * H + oh) * W + ow0] = st;
    }
}

// ---------------- D4: 7x7 reflect 16->3 + tanh + fused segment accum ---------
// v3: 16x32 tile (2 cols/thread) -> 2048 blocks, 8 blocks/CU, LDS ~19.9KB.
template<int CIN, int NCH>
__global__ void __launch_bounds__(256, 8)
conv7_seg(const float* __restrict__ x, const float* __restrict__ w,
          const float* __restrict__ bias,
          const float* __restrict__ mu, const float* __restrict__ rs,
          const int* __restrict__ inst, float* __restrict__ seg, int H, int W)
{
    __shared__ float wsm[CIN * 49 * 4];        // [ic][tap][4], 4th lane zero
    __shared__ float tile[NCH][22 * 39];       // 22 halo rows, stride 39
    __shared__ float smu[CIN], srs[CIN];
    __shared__ float ls[NUM_INST * 4];
    const int tid = threadIdx.x;
    const int b = blockIdx.z;

    if (tid < NUM_INST * 4) ls[tid] = 0.f;
    for (int idx = tid; idx < CIN * 49 * 4; idx += 256) {
        int ocp = idx & 3;
        int r   = idx >> 2;
        wsm[idx] = (ocp < 3) ? w[(size_t)ocp * CIN * 49 + r] : 0.f;
    }
    if (tid < CIN) { smu[tid] = mu[b * CIN + tid]; srs[tid] = rs[b * CIN + tid]; }

    const int oh_base = blockIdx.y * 16, ow_base = blockIdx.x * 32;
    const int row = tid >> 4;                  // 0..15
    const int col2 = (tid & 15) * 2;           // 0..30

    float acc[2][3];
#pragma unroll
    for (int c = 0; c < 3; ++c) {
        float bv = bias[c];
        acc[0][c] = bv; acc[1][c] = bv;
    }

    for (int ic0 = 0; ic0 < CIN; ic0 += NCH) {
        __syncthreads();
        for (int idx = tid; idx < NCH * 22 * 38; idx += 256) {
            int c  = idx / (22 * 38);
            int rr = idx % (22 * 38);
            int r  = rr / 38, cl = rr % 38;
            int gy = reflect_idx(oh_base - 3 + r, H);
            int gx = reflect_idx(ow_base - 3 + cl, W);
            int ic = ic0 + c;
            float v = x[((size_t)(b * CIN + ic)) * H * W + (size_t)gy * W + gx];
            v = fmaxf((v - smu[ic]) * srs[ic], 0.f);
            tile[c][r * 39 + cl] = v;
        }
        __syncthreads();
#pragma unroll
        for (int cc = 0; cc < NCH; ++cc) {
            const float* tp = &tile[cc][0];
            const float4* wp4 = (const float4*)&wsm[(ic0 + cc) * 49 * 4];
#pragma unroll
            for (int kh = 0; kh < 7; ++kh) {
                float rv[8];
#pragma unroll
                for (int i = 0; i < 8; ++i) rv[i] = tp[(row + kh) * 39 + col2 + i];
#pragma unroll
                for (int kw = 0; kw < 7; ++kw) {
                    float4 wv = wp4[kh * 7 + kw];
                    acc[0][0] += rv[kw] * wv.x;
                    acc[0][1] += rv[kw] * wv.y;
                    acc[0][2] += rv[kw] * wv.z;
                    acc[1][0] += rv[kw + 1] * wv.x;
                    acc[1][1] += rv[kw + 1] * wv.y;
                    acc[1][2] += rv[kw + 1] * wv.z;
                }
            }
        }
    }

    // epilogue: tanh + segment accumulate (no image write)
    const int oh = oh_base + row, ow0 = ow_base + col2;
    const int* ip = inst + (size_t)b * H * W + (size_t)oh * W + ow0;
    int2 ia = *(const int2*)ip;
    int idv[2] = {ia.x, ia.y};
#pragma unroll
    for (int j = 0; j < 2; ++j) {
        int base = idv[j] * 4;
        atomicAdd(&ls[base + 0], tanh_fast(acc[j][0]));
        atomicAdd(&ls[base + 1], tanh_fast(acc[j][1]));
        atomicAdd(&ls[base + 2], tanh_fast(acc[j][2]));
        atomicAdd(&ls[base + 3], 1.f);
    }
    __syncthreads();
    if (tid < NUM_INST * 4)
        atomicAdd(&seg[b * NUM_INST * 4 + tid], ls[tid]);
}

// ---------------- 3x3 stride-2 conv (scalar loads, K-split, OCPT=16) ---------
template<int CIN, int COUT, int OCPT, int KS, bool NORM>
__global__ void __launch_bounds__(256)
conv3_s2(const float* __restrict__ x, const float* __restrict__ w,
         const float* __restrict__ bias,
         const float* __restrict__ mu, const float* __restrict__ rs,
         float* __restrict__ y, size_t ystride, int Hin, int Win)
{
    const int Hout = Hin >> 1, Wout = Win >> 1;
    constexpr int CK = CIN / KS;
    __shared__ float wsm[CK * 9 * OCPT];     // [ic-local][tap][o]
    __shared__ float smu[CIN], srs[CIN];
    const int tid = threadIdx.x;
    const int NG = COUT / OCPT;
    const int z = blockIdx.z;
    const int ks = z % KS;
    const int ogb = z / KS;
    const int b = ogb / NG, g = ogb % NG;
    const int oc0 = g * OCPT;
    const int icbase = ks * CK;
    for (int idx = tid; idx < CK * 9 * OCPT; idx += 256) {
        int o = idx % OCPT;
        int r = idx / OCPT;
        wsm[idx] = w[(size_t)(oc0 + o) * CIN * 9 + (size_t)icbase * 9 + r];
    }
    if (NORM && tid < CIN) { smu[tid] = mu[b * CIN + tid]; srs[tid] = rs[b * CIN + tid]; }
    __syncthreads();

    const int ow = blockIdx.x * 16 + (tid & 15);
    const int oh = blockIdx.y * 16 + (tid >> 4);

    float acc[OCPT];
#pragma unroll
    for (int o = 0; o < OCPT; ++o) acc[o] = (ks == 0) ? bias[oc0 + o] : 0.f;

    for (int icl = 0; icl < CK; ++icl) {
        const int ic = icbase + icl;
        const float* xp = x + ((size_t)(b * CIN + ic)) * Hin * Win;
        float m = NORM ? smu[ic] : 0.f;
        float rr = NORM ? srs[ic] : 0.f;
#pragma unroll
        for (int kh = 0; kh < 3; ++kh) {
            int ih = 2 * oh + kh - 1;
            if (ih < 0 || ih >= Hin) continue;
#pragma unroll
            for (int kw = 0; kw < 3; ++kw) {
                int iw = 2 * ow + kw - 1;
                if (iw < 0 || iw >= Win) continue;
                float v = xp[(size_t)ih * Win + iw];
                if (NORM) v = fmaxf((v - m) * rr, 0.f);
                const float* wp = &wsm[(icl * 9 + kh * 3 + kw) * OCPT];
#pragma unroll
                for (int o = 0; o < OCPT; ++o) acc[o] += wp[o] * v;
            }
        }
    }
    float* yb = y + (size_t)ks * ystride;
    float* yp = yb + (((size_t)b * COUT + oc0) * Hout + oh) * Wout + ow;
#pragma unroll
    for (int o = 0; o < OCPT; ++o) yp[(size_t)o * Hout * Wout] = acc[o];
}

// ---------------- 3x3 stride-2 transposed conv (LDS + reg tiles, K-split) ----
template<int CIN, int COUT, int ICB, int KS>
__global__ void __launch_bounds__(256)
tconv3_v2(const float* __restrict__ x, const float* __restrict__ w,
          const float* __restrict__ bias,
          const float* __restrict__ mu, const float* __restrict__ rs,
          float* __restrict__ y, size_t ystride, int Hin, int Win)
{
    constexpr int OCB = 16;
    constexpr int NOG = COUT / OCB;
    constexpr int CK = CIN / KS;
    const int z = blockIdx.z;
    const int ks = z % KS;
    const int ogb = z / KS;
    const int b = ogb / NOG;
    const int ocb = (ogb % NOG) * OCB;
    const int r0 = blockIdx.y * 8, c0 = blockIdx.x * 32;
    const int Hout = Hin * 2, Wout = Win * 2;

    __shared__ float xt[ICB][9 * 36];
    __shared__ float wt[ICB][9][OCB];
    __shared__ float smu[CIN], srs[CIN];

    const int tid = threadIdx.x;
    if (tid < CIN) { smu[tid] = mu[b * CIN + tid]; srs[tid] = rs[b * CIN + tid]; }

    const int tid_s = tid & 63;
    const int og = tid >> 6;
    const int sr = tid_s >> 3;
    const int sc4 = (tid_s & 7) * 4;

    float acc[4][4][4];
#pragma unroll
    for (int o = 0; o < 4; ++o) {
        float bv = (ks == 0) ? bias[ocb + og * 4 + o] : 0.f;
#pragma unroll
        for (int pr = 0; pr < 4; ++pr)
#pragma unroll
            for (int p = 0; p < 4; ++p) acc[pr][o][p] = bv;
    }

    for (int ic0 = ks * CK; ic0 < (ks + 1) * CK; ic0 += ICB) {
        __syncthreads();
        for (int idx = tid; idx < ICB * 9 * 33; idx += 256) {
            int c  = idx / (9 * 33);
            int rr = idx % (9 * 33);
            int r  = rr / 33, col = rr % 33;
            int gr = r0 + r, gc = c0 + col;
            int ic = ic0 + c;
            float v = 0.f;
            if (gr < Hin && gc < Win) {
                v = x[((size_t)(b * CIN + ic)) * Hin * Win + (size_t)gr * Win + gc];
                v = fmaxf((v - smu[ic]) * srs[ic], 0.f);
            }
            xt[c][r * 36 + col] = v;
        }
        for (int idx = tid; idx < ICB * 9 * OCB; idx += 256) {
            int oc  = idx & (OCB - 1);
            int tap = (idx >> 4) % 9;
            int c   = idx / (9 * OCB);
            wt[c][tap][oc] = w[(size_t)(ocb + oc) * CIN * 9 + (size_t)(ic0 + c) * 9 + tap];
        }
        __syncthreads();

#pragma unroll 4
        for (int c = 0; c < ICB; ++c) {
            const float* xr = &xt[c][sr * 36 + sc4];
            float x0[5], x1[5];
            {
                float4 a = *(const float4*)xr;
                x0[0] = a.x; x0[1] = a.y; x0[2] = a.z; x0[3] = a.w; x0[4] = xr[4];
                float4 bq = *(const float4*)(xr + 36);
                x1[0] = bq.x; x1[1] = bq.y; x1[2] = bq.z; x1[3] = bq.w; x1[4] = xr[40];
            }
            const float* wp = &wt[c][0][og * 4];
#define TAPFMA(TAP, PAR, XV, SH)                                                   \
            {                                                                      \
                float4 wq = *(const float4*)(wp + (TAP) * OCB);                    \
                float wv[4] = {wq.x, wq.y, wq.z, wq.w};                            \
                _Pragma("unroll")                                                  \
                for (int o = 0; o < 4; ++o)                                        \
                    _Pragma("unroll")                                              \
                    for (int p = 0; p < 4; ++p)                                    \
                        acc[PAR][o][p] += wv[o] * XV[p + SH];                      \
            }
            TAPFMA(4, 0, x0, 0)
            TAPFMA(5, 1, x0, 0)
            TAPFMA(3, 1, x0, 1)
            TAPFMA(7, 2, x0, 0)
            TAPFMA(1, 2, x1, 0)
            TAPFMA(8, 3, x0, 0)
            TAPFMA(6, 3, x0, 1)
            TAPFMA(2, 3, x1, 0)
            TAPFMA(0, 3, x1, 1)
#undef TAPFMA
        }
    }

    float* yb = y + (size_t)ks * ystride;
    const int gr = r0 + sr, gc = c0 + sc4;
#pragma unroll
    for (int o = 0; o < 4; ++o) {
        int oc = ocb + og * 4 + o;
        float* yp = yb + (((size_t)(b * COUT + oc)) * Hout + 2 * gr) * Wout + 2 * gc;
        float4 e0, e1, d0, d1;
        e0.x = acc[0][o][0]; e0.y = acc[1][o][0]; e0.z = acc[0][o][1]; e0.w = acc[1][o][1];
        e1.x = acc[0][o][2]; e1.y = acc[1][o][2]; e1.z = acc[0][o][3]; e1.w = acc[1][o][3];
        d0.x = acc[2][o][0]; d0.y = acc[3][o][0]; d0.z = acc[2][o][1]; d0.w = acc[3][o][1];
        d1.x = acc[2][o][2]; d1.y = acc[3][o][2]; d1.z = acc[2][o][3]; d1.w = acc[3][o][3];
        *(float4*)yp = e0;
        *(float4*)(yp + 4) = e1;
        *(float4*)(yp + Wout) = d0;
        *(float4*)(yp + Wout + 4) = d1;
    }
}

// ---------------- reduce K-split partials + fused IN stats -------------------
template<int KS>
__global__ void __launch_bounds__(256)
reduce_stats(const float* __restrict__ parts, size_t pstride,
             float* __restrict__ out, float* __restrict__ acc, int HW)
{
    const int bc = blockIdx.x;
    const int chunk = HW / gridDim.y;
    const size_t base = (size_t)bc * HW + (size_t)blockIdx.y * chunk;
    float s = 0.f, ss = 0.f;
    const int n4 = chunk >> 2;
    for (int i = threadIdx.x; i < n4; i += 256) {
        float4 v = ((const float4*)(parts + base))[i];
#pragma unroll
        for (int k = 1; k < KS; ++k) {
            float4 u = ((const float4*)(parts + (size_t)k * pstride + base))[i];
            v.x += u.x; v.y += u.y; v.z += u.z; v.w += u.w;
        }
        ((float4*)(out + base))[i] = v;
        s += v.x + v.y + v.z + v.w;
        ss += v.x * v.x + v.y * v.y + v.z * v.z + v.w * v.w;
    }
#pragma unroll
    for (int off = 32; off; off >>= 1) {
        s += __shfl_down(s, off);
        ss += __shfl_down(ss, off);
    }
    __shared__ float rbuf[8];
    const int wid = threadIdx.x >> 6;
    if ((threadIdx.x & 63) == 0) { rbuf[wid] = s; rbuf[4 + wid] = ss; }
    __syncthreads();
    if (threadIdx.x == 0) {
        s = rbuf[0] + rbuf[1] + rbuf[2] + rbuf[3];
        ss = rbuf[4] + rbuf[5] + rbuf[6] + rbuf[7];
        atomicAdd(&acc[bc], s);
        atomicAdd(&acc[512 + bc], ss);
    }
}

// ---------------- instance-norm stats: partial (atomic) + finalize -----------
__global__ void __launch_bounds__(256)
in_stats_partial(const float* __restrict__ y, float* __restrict__ acc, int HW)
{
    const int bc = blockIdx.x;
    const int chunk = HW / gridDim.y;
    const float* p = y + (size_t)bc * HW + (size_t)blockIdx.y * chunk;
    float s = 0.f, ss = 0.f;
    const float4* p4 = (const float4*)p;
    const int n4 = chunk >> 2;
    for (int i = threadIdx.x; i < n4; i += 256) {
        float4 v = p4[i];
        s += v.x + v.y + v.z + v.w;
        ss += v.x * v.x + v.y * v.y + v.z * v.z + v.w * v.w;
    }
#pragma unroll
    for (int off = 32; off; off >>= 1) {
        s += __shfl_down(s, off);
        ss += __shfl_down(ss, off);
    }
    __shared__ float rbuf[8];
    const int wid = threadIdx.x >> 6;
    if ((threadIdx.x & 63) == 0) { rbuf[wid] = s; rbuf[4 + wid] = ss; }
    __syncthreads();
    if (threadIdx.x == 0) {
        s = rbuf[0] + rbuf[1] + rbuf[2] + rbuf[3];
        ss = rbuf[4] + rbuf[5] + rbuf[6] + rbuf[7];
        atomicAdd(&acc[bc], s);
        atomicAdd(&acc[512 + bc], ss);
    }
}

__global__ void in_stats_final(const float* __restrict__ acc,
                               float* __restrict__ mu, float* __restrict__ rs,
                               int BC, float invHW)
{
    int i = blockIdx.x * 256 + threadIdx.x;
    if (i < BC) {
        float m = acc[i] * invHW;
        float var = fmaxf(acc[512 + i] * invHW - m * m, 0.f);
        mu[i] = m;
        rs[i] = rsqrtf(var + EPS_IN);
    }
}

// ---------------- segment pooling tail ---------------------------------------
__global__ void zero_ws_k(float* __restrict__ p, int n)
{
    int i = blockIdx.x * 256 + threadIdx.x;
    if (i < n) p[i] = 0.f;
}

__global__ void seg_means_k(const float* __restrict__ seg, float* __restrict__ means)
{
    int i = threadIdx.x;
    if (i < 2 * NUM_INST * 3) {
        int bi = i / 3, c = i % 3;
        float cnt = seg[bi * 4 + 3];
        means[i] = seg[bi * 4 + c] / fmaxf(cnt, 1.f);
    }
}

__global__ void __launch_bounds__(256)
seg_scatter(const int* __restrict__ inst, const float* __restrict__ means,
            float* __restrict__ out, int HW)
{
    const int b = blockIdx.y;
    for (int i = blockIdx.x * 256 + threadIdx.x; i < HW; i += gridDim.x * 256) {
        int id = inst[(size_t)b * HW + i];
        const float* m = &means[(b * NUM_INST + id) * 3];
        out[((size_t)b * 3 + 0) * HW + i] = m[0];
        out[((size_t)b * 3 + 1) * HW + i] = m[1];
        out[((size_t)b * 3 + 2) * HW + i] = m[2];
    }
}

// ---------------- driver -----------------------------------------------------
extern "C" void kernel_launch(void* const* d_in, const int* in_sizes, int n_in,
                              void* d_out, int out_size, void* d_ws, size_t ws_size,
                              hipStream_t stream)
{
    const float* x_in = (const float*)d_in[0];
    const int* inst = (const int*)d_in[1];
    const float* e0w = (const float*)d_in[2];  const float* e0b = (const float*)d_in[3];
    const float* e1w = (const float*)d_in[4];  const float* e1b = (const float*)d_in[5];
    const float* e2w = (const float*)d_in[6];  const float* e2b = (const float*)d_in[7];
    const float* e3w = (const float*)d_in[8];  const float* e3b = (const float*)d_in[9];
    const float* e4w = (const float*)d_in[10]; const float* e4b = (const float*)d_in[11];
    const float* d0w = (const float*)d_in[12]; const float* d0b = (const float*)d_in[13];
    const float* d1w = (const float*)d_in[14]; const float* d1b = (const float*)d_in[15];
    const float* d2w = (const float*)d_in[16]; const float* d2b = (const float*)d_in[17];
    const float* d3w = (const float*)d_in[18]; const float* d3b = (const float*)d_in[19];
    const float* d4w = (const float*)d_in[20]; const float* d4b = (const float*)d_in[21];
    float* outp = (float*)d_out;

    float* bufA = (float*)d_ws;                       // 16777216 floats
    float* bufB = bufA + 16777216;                    // 8388608 floats
    float* st   = bufB + 8388608;                     // 9 layers x 1024 (mu|rs)
    float* acc  = st + 9 * 1024;                      // 9 layers x 1024 (sum|ss)
    float* seg  = acc + 9 * 1024;                     // 2*32*4
    float* means = seg + 2 * NUM_INST * 4;            // 2*32*3

    const dim3 blk(256);
    const int H = 512, W = 1024;

    {
        int nz = 9 * 1024 + 2 * NUM_INST * 4;
        zero_ws_k<<<dim3((nz + 255) / 256), blk, 0, stream>>>(acc, nz);
    }

#define STATS(buf, L, C, HWv)                                                        \
    in_stats_partial<<<dim3(2 * (C), 8), blk, 0, stream>>>((buf), acc + (L) * 1024, (HWv)); \
    in_stats_final<<<dim3(2), blk, 0, stream>>>(acc + (L) * 1024, st + (L) * 1024,          \
                                                st + (L) * 1024 + 512, 2 * (C),             \
                                                1.0f / (HWv));

    // L0: e0 7x7 reflect, 3->16 -> bufA (spill-free kernel, 8 blocks/CU)
    conv7_l0<3, 16><<<dim3(W / 16, H / 32, 2), blk, 0, stream>>>(
        x_in, e0w, e0b, bufA, H, W);
    STATS(bufA, 0, 16, H * W);

    // L1: 16->32 -> bufB (OCPT=16, NG=2)
    conv3_s2<16, 32, 16, 1, true><<<dim3(32, 16, 2 * 2), blk, 0, stream>>>(
        bufA, e1w, e1b, st + 0 * 1024, st + 0 * 1024 + 512, bufB, 0, 512, 1024);
    STATS(bufB, 1, 32, 256 * 512);

    // L2: 32->64 -> bufA[0..4.2M) (OCPT=16, NG=4)
    conv3_s2<32, 64, 16, 1, true><<<dim3(16, 8, 2 * 4), blk, 0, stream>>>(
        bufB, e2w, e2b, st + 1 * 1024, st + 1 * 1024 + 512, bufA, 0, 256, 512);
    STATS(bufA, 2, 64, 128 * 256);

    // L3: 64->128, KS=2, OCPT=16 (NG=8). in bufA[0..4.2M);
    // partials bufB[2.1M..6.3M); out -> bufB[0..2.1M)
    {
        const size_t PS = 2097152;                    // 2*128*64*128
        float* parts = bufB + 2097152;
        conv3_s2<64, 128, 16, 2, true><<<dim3(8, 4, 2 * 8 * 2), blk, 0, stream>>>(
            bufA, e3w, e3b, st + 2 * 1024, st + 2 * 1024 + 512, parts, PS, 128, 256);
        reduce_stats<2><<<dim3(2 * 128, 8), blk, 0, stream>>>(
            parts, PS, bufB, acc + 3 * 1024, 64 * 128);
        in_stats_final<<<dim3(2), blk, 0, stream>>>(acc + 3 * 1024, st + 3 * 1024,
                                                    st + 3 * 1024 + 512, 2 * 128,
                                                    1.0f / (64 * 128));
    }

    // L4: 128->256, KS=4, OCPT=16 (NG=16). in bufB[0..2.1M);
    // partials bufA[1M..5M); out -> bufA[0..1M)
    {
        const size_t PS = 1048576;                    // 2*256*32*64
        float* parts = bufA + 1048576;
        conv3_s2<128, 256, 16, 4, true><<<dim3(4, 2, 2 * 16 * 4), blk, 0, stream>>>(
            bufB, e4w, e4b, st + 3 * 1024, st + 3 * 1024 + 512, parts, PS, 64, 128);
        reduce_stats<4><<<dim3(2 * 256, 8), blk, 0, stream>>>(
            parts, PS, bufA, acc + 4 * 1024, 32 * 64);
        in_stats_final<<<dim3(2), blk, 0, stream>>>(acc + 4 * 1024, st + 4 * 1024,
                                                    st + 4 * 1024 + 512, 2 * 256,
                                                    1.0f / (32 * 64));
    }

    // D0: tconv 256->128, KS=4. in bufA[0..1M); partials bufA[2M..10.4M);
    // out -> bufB[0..2.1M)
    {
        const size_t PS = 2097152;
        float* parts = bufA + 2097152;
        tconv3_v2<256, 128, 16, 4><<<dim3(2, 4, 2 * 8 * 4), blk, 0, stream>>>(
            bufA, d0w, d0b, st + 4 * 1024, st + 4 * 1024 + 512, parts, PS, 32, 64);
        reduce_stats<4><<<dim3(2 * 128, 8), blk, 0, stream>>>(
            parts, PS, bufB, acc + 5 * 1024, 64 * 128);
        in_stats_final<<<dim3(2), blk, 0, stream>>>(acc + 5 * 1024, st + 5 * 1024,
                                                    st + 5 * 1024 + 512, 2 * 128,
                                                    1.0f / (64 * 128));
    }

    // D1: tconv 128->64, KS=2. in bufB[0..2.1M); partials bufA[8.39M..16.78M);
    // out -> bufA[0..4.2M)
    {
        const size_t PS = 4194304;
        float* parts = bufA + 8388608;
        tconv3_v2<128, 64, 16, 2><<<dim3(4, 8, 2 * 4 * 2), blk, 0, stream>>>(
            bufB, d1w, d1b, st + 5 * 1024, st + 5 * 1024 + 512, parts, PS, 64, 128);
        reduce_stats<2><<<dim3(2 * 64, 8), blk, 0, stream>>>(
            parts, PS, bufA, acc + 6 * 1024, 128 * 256);
        in_stats_final<<<dim3(2), blk, 0, stream>>>(acc + 6 * 1024, st + 6 * 1024,
                                                    st + 6 * 1024 + 512, 2 * 64,
                                                    1.0f / (128 * 256));
    }

    // D2: tconv 64->32. in bufA[0..4.2M) -> bufB[0..8.39M)
    tconv3_v2<64, 32, 16, 1><<<dim3(8, 16, 2 * 2), blk, 0, stream>>>(
        bufA, d2w, d2b, st + 6 * 1024, st + 6 * 1024 + 512, bufB, 0, 128, 256);
    STATS(bufB, 7, 32, 256 * 512);

    // D3: tconv 32->16. in bufB -> bufA (full)
    tconv3_v2<32, 16, 16, 1><<<dim3(16, 32, 2), blk, 0, stream>>>(
        bufB, d3w, d3b, st + 7 * 1024, st + 7 * 1024 + 512, bufA, 0, 256, 512);
    STATS(bufA, 8, 16, H * W);

    // D4: 7x7 reflect 16->3 + tanh + fused segment accumulation (no image write)
    conv7_seg<16, 2><<<dim3(W / 32, H / 16, 2), blk, 0, stream>>>(
        bufA, d4w, d4b, st + 8 * 1024, st + 8 * 1024 + 512, inst, seg, H, W);

    // segment means + scatter
    seg_means_k<<<dim3(1), blk, 0, stream>>>(seg, means);
    seg_scatter<<<dim3(512, 2), blk, 0, stream>>>(inst, means, outp, H * W);

#undef STATS
}

// Round 19
// 946.680 us; speedup vs baseline: 1.0803x; 1.0803x over previous
//
#include <hip/hip_runtime.h>
#include <cstddef>

#define NUM_INST 32
#define EPS_IN 1e-5f

__device__ __forceinline__ int reflect_idx(int i, int n) {
    if (i < 0) i = -i;
    else if (i >= n) i = 2 * n - 2 - i;
    return i;
}

__device__ __forceinline__ float tanh_fast(float v) {
    float a = fminf(fmaxf(v, -9.f), 9.f);
    float e = __expf(2.f * a);
    return (e - 1.f) / (e + 1.f);
}

// ---------------- L0: 7x7 reflect conv 3->16, spill-free (acc[2][16]) --------
// (256,8): 8 blocks/CU (LDS 19.9KB x 8 = 159.4KB).
template<int CIN, int COUT>
__global__ void __launch_bounds__(256, 8)
conv7_l0(const float* __restrict__ x, const float* __restrict__ w,
         const float* __restrict__ bias, float* __restrict__ y, int H, int W)
{
    __shared__ float wsm[CIN * 49 * COUT];     // [ic][tap][oc]
    __shared__ float tile[CIN][38 * 23];       // 38 rows x 22 cols, stride 23
    const int tid = threadIdx.x;
    const int b = blockIdx.z;

    for (int idx = tid; idx < CIN * 49 * COUT; idx += 256) {
        int oc = idx % COUT;
        int r  = idx / COUT;
        wsm[idx] = w[(size_t)oc * CIN * 49 + r];
    }
    const int oh_base = blockIdx.y * 32, ow_base = blockIdx.x * 16;
    for (int idx = tid; idx < CIN * 38 * 22; idx += 256) {
        int c  = idx / (38 * 22);
        int rr = idx % (38 * 22);
        int r  = rr / 22, col = rr % 22;
        int gy = reflect_idx(oh_base - 3 + r, H);
        int gx = reflect_idx(ow_base - 3 + col, W);
        tile[c][r * 23 + col] = x[((size_t)(b * CIN + c)) * H * W + (size_t)gy * W + gx];
    }
    __syncthreads();

    const int row = tid >> 3;
    const int col2 = (tid & 7) * 2;

    float acc[2][COUT];
#pragma unroll
    for (int o = 0; o < COUT; ++o) {
        float bv = bias[o];
        acc[0][o] = bv; acc[1][o] = bv;
    }

#pragma unroll
    for (int ic = 0; ic < CIN; ++ic) {
        const float* tp = &tile[ic][0];
        const float4* wp4 = (const float4*)&wsm[ic * 49 * COUT];
#pragma unroll
        for (int kh = 0; kh < 7; ++kh) {
            float rv[8];
#pragma unroll
            for (int i = 0; i < 8; ++i) rv[i] = tp[(row + kh) * 23 + col2 + i];
#pragma unroll
            for (int kw = 0; kw < 7; ++kw) {
#pragma unroll
                for (int o4 = 0; o4 < COUT / 4; ++o4) {
                    float4 wv = wp4[(kh * 7 + kw) * (COUT / 4) + o4];
                    acc[0][o4 * 4 + 0] += rv[kw] * wv.x;
                    acc[0][o4 * 4 + 1] += rv[kw] * wv.y;
                    acc[0][o4 * 4 + 2] += rv[kw] * wv.z;
                    acc[0][o4 * 4 + 3] += rv[kw] * wv.w;
                    acc[1][o4 * 4 + 0] += rv[kw + 1] * wv.x;
                    acc[1][o4 * 4 + 1] += rv[kw + 1] * wv.y;
                    acc[1][o4 * 4 + 2] += rv[kw + 1] * wv.z;
                    acc[1][o4 * 4 + 3] += rv[kw + 1] * wv.w;
                }
            }
        }
    }

    const int oh = oh_base + row, ow0 = ow_base + col2;
#pragma unroll
    for (int o = 0; o < COUT; ++o) {
        float2 st;
        st.x = acc[0][o]; st.y = acc[1][o];
        *(float2*)&y[(((size_t)b * COUT + o) * H + oh) * W + ow0] = st;
    }
}

// ---------------- D4: 7x7 reflect 16->3 + tanh + fused segment accum ---------
// (256,6): 6 blocks/CU (LDS 25.1KB x 6 = 150.5KB).
template<int CIN, int NCH>
__global__ void __launch_bounds__(256, 6)
conv7_seg(const float* __restrict__ x, const float* __restrict__ w,
          const float* __restrict__ bias,
          const float* __restrict__ mu, const float* __restrict__ rs,
          const int* __restrict__ inst, float* __restrict__ seg, int H, int W)
{
    __shared__ float wsm[CIN * 49 * 4];        // [ic][tap][4], 4th lane zero
    __shared__ float tile[NCH][38 * 39];       // stride 39
    __shared__ float smu[CIN], srs[CIN];
    __shared__ float ls[NUM_INST * 4];
    const int tid = threadIdx.x;
    const int b = blockIdx.z;

    if (tid < NUM_INST * 4) ls[tid] = 0.f;
    for (int idx = tid; idx < CIN * 49 * 4; idx += 256) {
        int ocp = idx & 3;
        int r   = idx >> 2;
        wsm[idx] = (ocp < 3) ? w[(size_t)ocp * CIN * 49 + r] : 0.f;
    }
    if (tid < CIN) { smu[tid] = mu[b * CIN + tid]; srs[tid] = rs[b * CIN + tid]; }

    const int oh_base = blockIdx.y * 32, ow_base = blockIdx.x * 32;
    const int row = tid >> 3;                  // 0..31
    const int col4 = (tid & 7) * 4;            // 0..28

    float acc[4][3];
#pragma unroll
    for (int c = 0; c < 3; ++c) {
        float bv = bias[c];
#pragma unroll
        for (int j = 0; j < 4; ++j) acc[j][c] = bv;
    }

    for (int ic0 = 0; ic0 < CIN; ic0 += NCH) {
        __syncthreads();
        for (int idx = tid; idx < NCH * 38 * 38; idx += 256) {
            int c  = idx / (38 * 38);
            int rr = idx % (38 * 38);
            int r  = rr / 38, cl = rr % 38;
            int gy = reflect_idx(oh_base - 3 + r, H);
            int gx = reflect_idx(ow_base - 3 + cl, W);
            int ic = ic0 + c;
            float v = x[((size_t)(b * CIN + ic)) * H * W + (size_t)gy * W + gx];
            v = fmaxf((v - smu[ic]) * srs[ic], 0.f);
            tile[c][r * 39 + cl] = v;
        }
        __syncthreads();
#pragma unroll
        for (int cc = 0; cc < NCH; ++cc) {
            const float* tp = &tile[cc][0];
            const float4* wp4 = (const float4*)&wsm[(ic0 + cc) * 49 * 4];
#pragma unroll
            for (int kh = 0; kh < 7; ++kh) {
                float rv[10];
#pragma unroll
                for (int i = 0; i < 10; ++i) rv[i] = tp[(row + kh) * 39 + col4 + i];
#pragma unroll
                for (int kw = 0; kw < 7; ++kw) {
                    float4 wv = wp4[kh * 7 + kw];
#pragma unroll
                    for (int j = 0; j < 4; ++j) {
                        acc[j][0] += rv[kw + j] * wv.x;
                        acc[j][1] += rv[kw + j] * wv.y;
                        acc[j][2] += rv[kw + j] * wv.z;
                    }
                }
            }
        }
    }

    // epilogue: tanh + segment accumulate (no image write)
    const int oh = oh_base + row, ow0 = ow_base + col4;
    const int* ip = inst + (size_t)b * H * W + (size_t)oh * W + ow0;
    int4 ia = *(const int4*)ip;
    int idv[4] = {ia.x, ia.y, ia.z, ia.w};
#pragma unroll
    for (int j = 0; j < 4; ++j) {
        int base = idv[j] * 4;
        atomicAdd(&ls[base + 0], tanh_fast(acc[j][0]));
        atomicAdd(&ls[base + 1], tanh_fast(acc[j][1]));
        atomicAdd(&ls[base + 2], tanh_fast(acc[j][2]));
        atomicAdd(&ls[base + 3], 1.f);
    }
    __syncthreads();
    if (tid < NUM_INST * 4)
        atomicAdd(&seg[b * NUM_INST * 4 + tid], ls[tid]);
}

// ---------------- 3x3 stride-2 conv (scalar loads, K-split, OCPT=16) ---------
template<int CIN, int COUT, int OCPT, int KS, bool NORM>
__global__ void __launch_bounds__(256)
conv3_s2(const float* __restrict__ x, const float* __restrict__ w,
         const float* __restrict__ bias,
         const float* __restrict__ mu, const float* __restrict__ rs,
         float* __restrict__ y, size_t ystride, int Hin, int Win)
{
    const int Hout = Hin >> 1, Wout = Win >> 1;
    constexpr int CK = CIN / KS;
    __shared__ float wsm[CK * 9 * OCPT];     // [ic-local][tap][o]
    __shared__ float smu[CIN], srs[CIN];
    const int tid = threadIdx.x;
    const int NG = COUT / OCPT;
    const int z = blockIdx.z;
    const int ks = z % KS;
    const int ogb = z / KS;
    const int b = ogb / NG, g = ogb % NG;
    const int oc0 = g * OCPT;
    const int icbase = ks * CK;
    for (int idx = tid; idx < CK * 9 * OCPT; idx += 256) {
        int o = idx % OCPT;
        int r = idx / OCPT;
        wsm[idx] = w[(size_t)(oc0 + o) * CIN * 9 + (size_t)icbase * 9 + r];
    }
    if (NORM && tid < CIN) { smu[tid] = mu[b * CIN + tid]; srs[tid] = rs[b * CIN + tid]; }
    __syncthreads();

    const int ow = blockIdx.x * 16 + (tid & 15);
    const int oh = blockIdx.y * 16 + (tid >> 4);

    float acc[OCPT];
#pragma unroll
    for (int o = 0; o < OCPT; ++o) acc[o] = (ks == 0) ? bias[oc0 + o] : 0.f;

    for (int icl = 0; icl < CK; ++icl) {
        const int ic = icbase + icl;
        const float* xp = x + ((size_t)(b * CIN + ic)) * Hin * Win;
        float m = NORM ? smu[ic] : 0.f;
        float rr = NORM ? srs[ic] : 0.f;
#pragma unroll
        for (int kh = 0; kh < 3; ++kh) {
            int ih = 2 * oh + kh - 1;
            if (ih < 0 || ih >= Hin) continue;
#pragma unroll
            for (int kw = 0; kw < 3; ++kw) {
                int iw = 2 * ow + kw - 1;
                if (iw < 0 || iw >= Win) continue;
                float v = xp[(size_t)ih * Win + iw];
                if (NORM) v = fmaxf((v - m) * rr, 0.f);
                const float* wp = &wsm[(icl * 9 + kh * 3 + kw) * OCPT];
#pragma unroll
                for (int o = 0; o < OCPT; ++o) acc[o] += wp[o] * v;
            }
        }
    }
    float* yb = y + (size_t)ks * ystride;
    float* yp = yb + (((size_t)b * COUT + oc0) * Hout + oh) * Wout + ow;
#pragma unroll
    for (int o = 0; o < OCPT; ++o) yp[(size_t)o * Hout * Wout] = acc[o];
}

// ---------------- 3x3 stride-2 transposed conv (LDS + reg tiles, K-split) ----
template<int CIN, int COUT, int ICB, int KS>
__global__ void __launch_bounds__(256)
tconv3_v2(const float* __restrict__ x, const float* __restrict__ w,
          const float* __restrict__ bias,
          const float* __restrict__ mu, const float* __restrict__ rs,
          float* __restrict__ y, size_t ystride, int Hin, int Win)
{
    constexpr int OCB = 16;
    constexpr int NOG = COUT / OCB;
    constexpr int CK = CIN / KS;
    const int z = blockIdx.z;
    const int ks = z % KS;
    const int ogb = z / KS;
    const int b = ogb / NOG;
    const int ocb = (ogb % NOG) * OCB;
    const int r0 = blockIdx.y * 8, c0 = blockIdx.x * 32;
    const int Hout = Hin * 2, Wout = Win * 2;

    __shared__ float xt[ICB][9 * 36];
    __shared__ float wt[ICB][9][OCB];
    __shared__ float smu[CIN], srs[CIN];

    const int tid = threadIdx.x;
    if (tid < CIN) { smu[tid] = mu[b * CIN + tid]; srs[tid] = rs[b * CIN + tid]; }

    const int tid_s = tid & 63;
    const int og = tid >> 6;
    const int sr = tid_s >> 3;
    const int sc4 = (tid_s & 7) * 4;

    float acc[4][4][4];
#pragma unroll
    for (int o = 0; o < 4; ++o) {
        float bv = (ks == 0) ? bias[ocb + og * 4 + o] : 0.f;
#pragma unroll
        for (int pr = 0; pr < 4; ++pr)
#pragma unroll
            for (int p = 0; p < 4; ++p) acc[pr][o][p] = bv;
    }

    for (int ic0 = ks * CK; ic0 < (ks + 1) * CK; ic0 += ICB) {
        __syncthreads();
        for (int idx = tid; idx < ICB * 9 * 33; idx += 256) {
            int c  = idx / (9 * 33);
            int rr = idx % (9 * 33);
            int r  = rr / 33, col = rr % 33;
            int gr = r0 + r, gc = c0 + col;
            int ic = ic0 + c;
            float v = 0.f;
            if (gr < Hin && gc < Win) {
                v = x[((size_t)(b * CIN + ic)) * Hin * Win + (size_t)gr * Win + gc];
                v = fmaxf((v - smu[ic]) * srs[ic], 0.f);
            }
            xt[c][r * 36 + col] = v;
        }
        for (int idx = tid; idx < ICB * 9 * OCB; idx += 256) {
            int oc  = idx & (OCB - 1);
            int tap = (idx >> 4) % 9;
            int c   = idx / (9 * OCB);
            wt[c][tap][oc] = w[(size_t)(ocb + oc) * CIN * 9 + (size_t)(ic0 + c) * 9 + tap];
        }
        __syncthreads();

#pragma unroll 4
        for (int c = 0; c < ICB; ++c) {
            const float* xr = &xt[c][sr * 36 + sc4];
            float x0[5], x1[5];
            {
                float4 a = *(const float4*)xr;
                x0[0] = a.x; x0[1] = a.y; x0[2] = a.z; x0[3] = a.w; x0[4] = xr[4];
                float4 bq = *(const float4*)(xr + 36);
                x1[0] = bq.x; x1[1] = bq.y; x1[2] = bq.z; x1[3] = bq.w; x1[4] = xr[40];
            }
            const float* wp = &wt[c][0][og * 4];
#define TAPFMA(TAP, PAR, XV, SH)                                                   \
            {                                                                      \
                float4 wq = *(const float4*)(wp + (TAP) * OCB);                    \
                float wv[4] = {wq.x, wq.y, wq.z, wq.w};                            \
                _Pragma("unroll")                                                  \
                for (int o = 0; o < 4; ++o)                                        \
                    _Pragma("unroll")                                              \
                    for (int p = 0; p < 4; ++p)                                    \
                        acc[PAR][o][p] += wv[o] * XV[p + SH];                      \
            }
            TAPFMA(4, 0, x0, 0)
            TAPFMA(5, 1, x0, 0)
            TAPFMA(3, 1, x0, 1)
            TAPFMA(7, 2, x0, 0)
            TAPFMA(1, 2, x1, 0)
            TAPFMA(8, 3, x0, 0)
            TAPFMA(6, 3, x0, 1)
            TAPFMA(2, 3, x1, 0)
            TAPFMA(0, 3, x1, 1)
#undef TAPFMA
        }
    }

    float* yb = y + (size_t)ks * ystride;
    const int gr = r0 + sr, gc = c0 + sc4;
#pragma unroll
    for (int o = 0; o < 4; ++o) {
        int oc = ocb + og * 4 + o;
        float* yp = yb + (((size_t)(b * COUT + oc)) * Hout + 2 * gr) * Wout + 2 * gc;
        float4 e0, e1, d0, d1;
        e0.x = acc[0][o][0]; e0.y = acc[1][o][0]; e0.z = acc[0][o][1]; e0.w = acc[1][o][1];
        e1.x = acc[0][o][2]; e1.y = acc[1][o][2]; e1.z = acc[0][o][3]; e1.w = acc[1][o][3];
        d0.x = acc[2][o][0]; d0.y = acc[3][o][0]; d0.z = acc[2][o][1]; d0.w = acc[3][o][1];
        d1.x = acc[2][o][2]; d1.y = acc[3][o][2]; d1.z = acc[2][o][3]; d1.w = acc[3][o][3];
        *(float4*)yp = e0;
        *(float4*)(yp + 4) = e1;
        *(float4*)(yp + Wout) = d0;
        *(float4*)(yp + Wout + 4) = d1;
    }
}

// ---------------- reduce K-split partials + fused IN stats -------------------
template<int KS>
__global__ void __launch_bounds__(256)
reduce_stats(const float* __restrict__ parts, size_t pstride,
             float* __restrict__ out, float* __restrict__ acc, int HW)
{
    const int bc = blockIdx.x;
    const int chunk = HW / gridDim.y;
    const size_t base = (size_t)bc * HW + (size_t)blockIdx.y * chunk;
    float s = 0.f, ss = 0.f;
    const int n4 = chunk >> 2;
    for (int i = threadIdx.x; i < n4; i += 256) {
        float4 v = ((const float4*)(parts + base))[i];
#pragma unroll
        for (int k = 1; k < KS; ++k) {
            float4 u = ((const float4*)(parts + (size_t)k * pstride + base))[i];
            v.x += u.x; v.y += u.y; v.z += u.z; v.w += u.w;
        }
        ((float4*)(out + base))[i] = v;
        s += v.x + v.y + v.z + v.w;
        ss += v.x * v.x + v.y * v.y + v.z * v.z + v.w * v.w;
    }
#pragma unroll
    for (int off = 32; off; off >>= 1) {
        s += __shfl_down(s, off);
        ss += __shfl_down(ss, off);
    }
    __shared__ float rbuf[8];
    const int wid = threadIdx.x >> 6;
    if ((threadIdx.x & 63) == 0) { rbuf[wid] = s; rbuf[4 + wid] = ss; }
    __syncthreads();
    if (threadIdx.x == 0) {
        s = rbuf[0] + rbuf[1] + rbuf[2] + rbuf[3];
        ss = rbuf[4] + rbuf[5] + rbuf[6] + rbuf[7];
        atomicAdd(&acc[bc], s);
        atomicAdd(&acc[512 + bc], ss);
    }
}

// ---------------- instance-norm stats: partial (atomic) + finalize -----------
__global__ void __launch_bounds__(256)
in_stats_partial(const float* __restrict__ y, float* __restrict__ acc, int HW)
{
    const int bc = blockIdx.x;
    const int chunk = HW / gridDim.y;
    const float* p = y + (size_t)bc * HW + (size_t)blockIdx.y * chunk;
    float s = 0.f, ss = 0.f;
    const float4* p4 = (const float4*)p;
    const int n4 = chunk >> 2;
    for (int i = threadIdx.x; i < n4; i += 256) {
        float4 v = p4[i];
        s += v.x + v.y + v.z + v.w;
        ss += v.x * v.x + v.y * v.y + v.z * v.z + v.w * v.w;
    }
#pragma unroll
    for (int off = 32; off; off >>= 1) {
        s += __shfl_down(s, off);
        ss += __shfl_down(ss, off);
    }
    __shared__ float rbuf[8];
    const int wid = threadIdx.x >> 6;
    if ((threadIdx.x & 63) == 0) { rbuf[wid] = s; rbuf[4 + wid] = ss; }
    __syncthreads();
    if (threadIdx.x == 0) {
        s = rbuf[0] + rbuf[1] + rbuf[2] + rbuf[3];
        ss = rbuf[4] + rbuf[5] + rbuf[6] + rbuf[7];
        atomicAdd(&acc[bc], s);
        atomicAdd(&acc[512 + bc], ss);
    }
}

__global__ void in_stats_final(const float* __restrict__ acc,
                               float* __restrict__ mu, float* __restrict__ rs,
                               int BC, float invHW)
{
    int i = blockIdx.x * 256 + threadIdx.x;
    if (i < BC) {
        float m = acc[i] * invHW;
        float var = fmaxf(acc[512 + i] * invHW - m * m, 0.f);
        mu[i] = m;
        rs[i] = rsqrtf(var + EPS_IN);
    }
}

// ---------------- segment pooling tail ---------------------------------------
__global__ void zero_ws_k(float* __restrict__ p, int n)
{
    int i = blockIdx.x * 256 + threadIdx.x;
    if (i < n) p[i] = 0.f;
}

__global__ void seg_means_k(const float* __restrict__ seg, float* __restrict__ means)
{
    int i = threadIdx.x;
    if (i < 2 * NUM_INST * 3) {
        int bi = i / 3, c = i % 3;
        float cnt = seg[bi * 4 + 3];
        means[i] = seg[bi * 4 + c] / fmaxf(cnt, 1.f);
    }
}

__global__ void __launch_bounds__(256)
seg_scatter(const int* __restrict__ inst, const float* __restrict__ means,
            float* __restrict__ out, int HW)
{
    const int b = blockIdx.y;
    for (int i = blockIdx.x * 256 + threadIdx.x; i < HW; i += gridDim.x * 256) {
        int id = inst[(size_t)b * HW + i];
        const float* m = &means[(b * NUM_INST + id) * 3];
        out[((size_t)b * 3 + 0) * HW + i] = m[0];
        out[((size_t)b * 3 + 1) * HW + i] = m[1];
        out[((size_t)b * 3 + 2) * HW + i] = m[2];
    }
}

// ---------------- driver -----------------------------------------------------
extern "C" void kernel_launch(void* const* d_in, const int* in_sizes, int n_in,
                              void* d_out, int out_size, void* d_ws, size_t ws_size,
                              hipStream_t stream)
{
    const float* x_in = (const float*)d_in[0];
    const int* inst = (const int*)d_in[1];
    const float* e0w = (const float*)d_in[2];  const float* e0b = (const float*)d_in[3];
    const float* e1w = (const float*)d_in[4];  const float* e1b = (const float*)d_in[5];
    const float* e2w = (const float*)d_in[6];  const float* e2b = (const float*)d_in[7];
    const float* e3w = (const float*)d_in[8];  const float* e3b = (const float*)d_in[9];
    const float* e4w = (const float*)d_in[10]; const float* e4b = (const float*)d_in[11];
    const float* d0w = (const float*)d_in[12]; const float* d0b = (const float*)d_in[13];
    const float* d1w = (const float*)d_in[14]; const float* d1b = (const float*)d_in[15];
    const float* d2w = (const float*)d_in[16]; const float* d2b = (const float*)d_in[17];
    const float* d3w = (const float*)d_in[18]; const float* d3b = (const float*)d_in[19];
    const float* d4w = (const float*)d_in[20]; const float* d4b = (const float*)d_in[21];
    float* outp = (float*)d_out;

    float* bufA = (float*)d_ws;                       // 16777216 floats
    float* bufB = bufA + 16777216;                    // 8388608 floats
    float* st   = bufB + 8388608;                     // 9 layers x 1024 (mu|rs)
    float* acc  = st + 9 * 1024;                      // 9 layers x 1024 (sum|ss)
    float* seg  = acc + 9 * 1024;                     // 2*32*4
    float* means = seg + 2 * NUM_INST * 4;            // 2*32*3

    const dim3 blk(256);
    const int H = 512, W = 1024;

    {
        int nz = 9 * 1024 + 2 * NUM_INST * 4;
        zero_ws_k<<<dim3((nz + 255) / 256), blk, 0, stream>>>(acc, nz);
    }

#define STATS(buf, L, C, HWv)                                                        \
    in_stats_partial<<<dim3(2 * (C), 8), blk, 0, stream>>>((buf), acc + (L) * 1024, (HWv)); \
    in_stats_final<<<dim3(2), blk, 0, stream>>>(acc + (L) * 1024, st + (L) * 1024,          \
                                                st + (L) * 1024 + 512, 2 * (C),             \
                                                1.0f / (HWv));

    // L0: e0 7x7 reflect, 3->16 -> bufA (spill-free kernel, 8 blocks/CU)
    conv7_l0<3, 16><<<dim3(W / 16, H / 32, 2), blk, 0, stream>>>(
        x_in, e0w, e0b, bufA, H, W);
    STATS(bufA, 0, 16, H * W);

    // L1: 16->32 -> bufB (OCPT=16, NG=2)
    conv3_s2<16, 32, 16, 1, true><<<dim3(32, 16, 2 * 2), blk, 0, stream>>>(
        bufA, e1w, e1b, st + 0 * 1024, st + 0 * 1024 + 512, bufB, 0, 512, 1024);
    STATS(bufB, 1, 32, 256 * 512);

    // L2: 32->64 -> bufA[0..4.2M) (OCPT=16, NG=4)
    conv3_s2<32, 64, 16, 1, true><<<dim3(16, 8, 2 * 4), blk, 0, stream>>>(
        bufB, e2w, e2b, st + 1 * 1024, st + 1 * 1024 + 512, bufA, 0, 256, 512);
    STATS(bufA, 2, 64, 128 * 256);

    // L3: 64->128, KS=2, OCPT=16 (NG=8). in bufA[0..4.2M);
    // partials bufB[2.1M..6.3M); out -> bufB[0..2.1M)
    {
        const size_t PS = 2097152;                    // 2*128*64*128
        float* parts = bufB + 2097152;
        conv3_s2<64, 128, 16, 2, true><<<dim3(8, 4, 2 * 8 * 2), blk, 0, stream>>>(
            bufA, e3w, e3b, st + 2 * 1024, st + 2 * 1024 + 512, parts, PS, 128, 256);
        reduce_stats<2><<<dim3(2 * 128, 8), blk, 0, stream>>>(
            parts, PS, bufB, acc + 3 * 1024, 64 * 128);
        in_stats_final<<<dim3(2), blk, 0, stream>>>(acc + 3 * 1024, st + 3 * 1024,
                                                    st + 3 * 1024 + 512, 2 * 128,
                                                    1.0f / (64 * 128));
    }

    // L4: 128->256, KS=4, OCPT=16 (NG=16). in bufB[0..2.1M);
    // partials bufA[1M..5M); out -> bufA[0..1M)
    {
        const size_t PS = 1048576;                    // 2*256*32*64
        float* parts = bufA + 1048576;
        conv3_s2<128, 256, 16, 4, true><<<dim3(4, 2, 2 * 16 * 4), blk, 0, stream>>>(
            bufB, e4w, e4b, st + 3 * 1024, st + 3 * 1024 + 512, parts, PS, 64, 128);
        reduce_stats<4><<<dim3(2 * 256, 8), blk, 0, stream>>>(
            parts, PS, bufA, acc + 4 * 1024, 32 * 64);
        in_stats_final<<<dim3(2), blk, 0, stream>>>(acc + 4 * 1024, st + 4 * 1024,
                                                    st + 4 * 1024 + 512, 2 * 256,
                                                    1.0f / (32 * 64));
    }

    // D0: tconv 256->128, KS=4. in bufA[0..1M); partials bufA[2M..10.4M);
    // out -> bufB[0..2.1M)
    {
        const size_t PS = 2097152;
        float* parts = bufA + 2097152;
        tconv3_v2<256, 128, 16, 4><<<dim3(2, 4, 2 * 8 * 4), blk, 0, stream>>>(
            bufA, d0w, d0b, st + 4 * 1024, st + 4 * 1024 + 512, parts, PS, 32, 64);
        reduce_stats<4><<<dim3(2 * 128, 8), blk, 0, stream>>>(
            parts, PS, bufB, acc + 5 * 1024, 64 * 128);
        in_stats_final<<<dim3(2), blk, 0, stream>>>(acc + 5 * 1024, st + 5 * 1024,
                                                    st + 5 * 1024 + 512, 2 * 128,
                                                    1.0f / (64 * 128));
    }

    // D1: tconv 128->64, KS=2. in bufB[0..2.1M); partials bufA[8.39M..16.78M);
    // out -> bufA[0..4.2M)
    {
        const size_t PS = 4194304;
        float* parts = bufA + 8388608;
        tconv3_v2<128, 64, 16, 2><<<dim3(4, 8, 2 * 4 * 2), blk, 0, stream>>>(
            bufB, d1w, d1b, st + 5 * 1024, st + 5 * 1024 + 512, parts, PS, 64, 128);
        reduce_stats<2><<<dim3(2 * 64, 8), blk, 0, stream>>>(
            parts, PS, bufA, acc + 6 * 1024, 128 * 256);
        in_stats_final<<<dim3(2), blk, 0, stream>>>(acc + 6 * 1024, st + 6 * 1024,
                                                    st + 6 * 1024 + 512, 2 * 64,
                                                    1.0f / (128 * 256));
    }

    // D2: tconv 64->32. in bufA[0..4.2M) -> bufB[0..8.39M)
    tconv3_v2<64, 32, 16, 1><<<dim3(8, 16, 2 * 2), blk, 0, stream>>>(
        bufA, d2w, d2b, st + 6 * 1024, st + 6 * 1024 + 512, bufB, 0, 128, 256);
    STATS(bufB, 7, 32, 256 * 512);

    // D3: tconv 32->16. in bufB -> bufA (full)
    tconv3_v2<32, 16, 16, 1><<<dim3(16, 32, 2), blk, 0, stream>>>(
        bufB, d3w, d3b, st + 7 * 1024, st + 7 * 1024 + 512, bufA, 0, 256, 512);
    STATS(bufA, 8, 16, H * W);

    // D4: 7x7 reflect 16->3 + tanh + fused segment accumulation (no image write)
    conv7_seg<16, 2><<<dim3(W / 32, H / 32, 2), blk, 0, stream>>>(
        bufA, d4w, d4b, st + 8 * 1024, st + 8 * 1024 + 512, inst, seg, H, W);

    // segment means + scatter
    seg_means_k<<<dim3(1), blk, 0, stream>>>(seg, means);
    seg_scatter<<<dim3(512, 2), blk, 0, stream>>>(inst, means, outp, H * W);

#undef STATS
}